// Round 14
// baseline (554.724 us; speedup 1.0000x reference)
//
#include <hip/hip_runtime.h>
#include <stdint.h>

typedef __attribute__((ext_vector_type(4))) int int4v;

// ---------- helpers ----------

__device__ __forceinline__ int pack4_rn(float4 v, float s) {
    int a = __float2int_rn(v.x * s) & 0xff;
    int b = __float2int_rn(v.y * s) & 0xff;
    int c = __float2int_rn(v.z * s) & 0xff;
    int d = __float2int_rn(v.w * s) & 0xff;
    return a | (b << 8) | (c << 16) | (d << 24);
}

__device__ __forceinline__ int bin4(float4 v) {
    int a = (v.x > 0.5f) ? 1 : 0;
    int b = (v.y > 0.5f) ? 1 : 0;
    int c = (v.z > 0.5f) ? 1 : 0;
    int d = (v.w > 0.5f) ? 1 : 0;
    return a | (b << 8) | (c << 16) | (d << 24);
}

// ---------- pre-pass: x (f32) -> per-row-quantized i8 + rscale ----------
// at BW floor (~25 us)

__global__ __launch_bounds__(256) void lb_quant_x(const float* __restrict__ x,
        signed char* __restrict__ xq, float* __restrict__ rscale, int K)
{
    const int row = blockIdx.x;
    const int tid = threadIdx.x;
    const float* xr = x + (size_t)row * K;

    float mx = 0.f;
    for (int i = tid * 4; i < K; i += 256 * 4) {
        float4 v = *(const float4*)(xr + i);
        mx = fmaxf(mx, fmaxf(fmaxf(fabsf(v.x), fabsf(v.y)),
                             fmaxf(fabsf(v.z), fabsf(v.w))));
    }
#pragma unroll
    for (int s = 32; s; s >>= 1) mx = fmaxf(mx, __shfl_xor(mx, s));
    __shared__ float wmax[4];
    if ((tid & 63) == 0) wmax[tid >> 6] = mx;
    __syncthreads();
    mx = fmaxf(fmaxf(wmax[0], wmax[1]), fmaxf(wmax[2], wmax[3]));

    const float s = (mx > 0.f) ? 127.f / mx : 0.f;
    if (tid == 0) rscale[row] = (mx > 0.f) ? mx * (1.f / 127.f) : 0.f;

    for (int i = tid * 16; i < K; i += 256 * 16) {
        float4 a = *(const float4*)(xr + i);
        float4 b = *(const float4*)(xr + i + 4);
        float4 c = *(const float4*)(xr + i + 8);
        float4 d = *(const float4*)(xr + i + 12);
        int4 o;
        o.x = pack4_rn(a, s); o.y = pack4_rn(b, s);
        o.z = pack4_rn(c, s); o.w = pack4_rn(d, s);
        *(int4*)(xq + (size_t)row * K + i) = o;
    }
}

// ---------- pre-pass: w (f32) -> binarized i8 {0,1} ----------

__global__ void lb_bin_w8(const float* __restrict__ w, int4* __restrict__ wq, long n16) {
    long i = (long)blockIdx.x * blockDim.x + threadIdx.x;
    long stride = (long)gridDim.x * blockDim.x;
    for (; i < n16; i += stride) {
        const float4* p = (const float4*)w + i * 4;
        float4 v0 = p[0], v1 = p[1], v2 = p[2], v3 = p[3];
        int4 o;
        o.x = bin4(v0); o.y = bin4(v1); o.z = bin4(v2); o.w = bin4(v3);
        wq[i] = o;
    }
}

// ---------- main GEMM (i8): NO-LDS direct-from-global, zero barriers ----------
// Diagnosis R2-R12: barrier-serialized [LDS-read -> MFMA] chain caps at ~45%.
// This kernel removes the mechanism entirely: each wave loads its 12 MFMA
// fragments (8 A + 4 B, 16B/lane, 16 fully-consumed 64B lines per load)
// straight from global (L1/L2/L3-served) into a depth-2 register double
// buffer. AITER K-loop shape: MFMA(F_cur) then issue loads(t+2)->F_cur;
// compiler emits counted vmcnt (never 0 mid-loop); NO s_barrier, NO LDS.
// Regs: acc 128 + frags 96 + addr ~20 = ~245 < 256 @ launch_bounds(256,2).
// Block = 4 waves (2 wr x 2 wc), tile 256x128; grid 1024, XCD-swizzled so
// blocks sharing an A-panel (1 MB) are L2-co-located.

#define BM 256
#define BN 128
#define BK 64

#define LOADF(AF, BF, T) do { \
    _Pragma("unroll") \
    for (int m_ = 0; m_ < 8; ++m_) \
        AF[m_] = *(const int4v*)(Ab + (size_t)m_ * 16 * K + (size_t)(T) * BK); \
    _Pragma("unroll") \
    for (int n_ = 0; n_ < 4; ++n_) \
        BF[n_] = *(const int4v*)(Bb + (size_t)n_ * 16 * K + (size_t)(T) * BK); \
} while (0)

#define MFMA32(AF, BF) do { \
    __builtin_amdgcn_s_setprio(1); \
    _Pragma("unroll") \
    for (int m_ = 0; m_ < 8; ++m_) { \
      _Pragma("unroll") \
      for (int n_ = 0; n_ < 4; ++n_) { \
        acc[m_][n_] = __builtin_amdgcn_mfma_i32_16x16x64_i8( \
            AF[m_], BF[n_], acc[m_][n_], 0, 0, 0); \
      } \
    } \
    __builtin_amdgcn_s_setprio(0); \
} while (0)

__global__ __launch_bounds__(256, 2) void lb_gemm_i8_direct(
    const signed char* __restrict__ A,   // M x K i8 (quantized x)
    const signed char* __restrict__ B,   // N x K i8 {0,1} (binarized weight)
    const float* __restrict__ rscale,    // M row dequant scales
    const float* __restrict__ bias,
    float* __restrict__ C,
    int M, int N, int K)
{
    const int tid  = threadIdx.x;
    const int lane = tid & 63;
    const int wave = tid >> 6;       // 0..3
    const int wr   = wave >> 1;      // 0..1 -> 128 output rows each
    const int wc   = wave & 1;       // 0..1 -> 64 output cols each

    // XCD-aware bijective swizzle (grid % 8 == 0 guaranteed by launcher)
    int nwg = gridDim.x;
    int bid = blockIdx.x;
    bid = (bid & 7) * (nwg >> 3) + (bid >> 3);

    const int ntiles = N / BN;
    const int brow = (bid / ntiles) * BM;
    const int bcol = (bid % ntiles) * BN;

    const int fr = lane & 15;
    const int fq = lane >> 4;        // k-group: 16B chunk within 64B

    // per-wave fragment base pointers (fragment m/n at +m*16*K / +n*16*K)
    const signed char* Ab = A + (size_t)(brow + wr * 128 + fr) * K + fq * 16;
    const signed char* Bb = B + (size_t)(bcol + wc * 64 + fr) * K + fq * 16;

    int4v acc[8][4];
#pragma unroll
    for (int i = 0; i < 8; ++i)
#pragma unroll
        for (int j = 0; j < 4; ++j)
            acc[i][j] = (int4v){0, 0, 0, 0};

    const int nk = K / BK;           // even, >= 4 (launcher guard)

    int4v aF0[8], bF0[4], aF1[8], bF1[4];
    LOADF(aF0, bF0, 0);
    LOADF(aF1, bF1, 1);

    for (int t = 0; t < nk; t += 2) {
        // compiler inserts counted vmcnt before first aF0 use (12 younger
        // F1 loads stay in flight); WAR on registers orders the re-load
        // after the MFMA cluster. No barriers anywhere.
        MFMA32(aF0, bF0);
        if (t + 2 < nk) LOADF(aF0, bF0, t + 2);
        MFMA32(aF1, bF1);
        if (t + 3 < nk) LOADF(aF1, bF1, t + 3);
    }

    // epilogue: C/D layout col = lane&15, row = (lane>>4)*4 + reg
    float bn[4];
#pragma unroll
    for (int n = 0; n < 4; ++n)
        bn[n] = bias[bcol + wc * 64 + n * 16 + fr];

#pragma unroll
    for (int m = 0; m < 8; ++m) {
#pragma unroll
        for (int j = 0; j < 4; ++j) {
            int row = brow + wr * 128 + m * 16 + fq * 4 + j;
            float rs = rscale[row];
#pragma unroll
            for (int n = 0; n < 4; ++n) {
                int col = bcol + wc * 64 + n * 16 + fr;
                C[(size_t)row * N + col] = (float)acc[m][n][j] * rs + bn[n];
            }
        }
    }
}

// ---------- fallback: correct fp32 tiled GEMM ----------

__global__ __launch_bounds__(256) void lb_gemm_fb(
    const float* __restrict__ x, const float* __restrict__ w,
    const float* __restrict__ bias, float* __restrict__ C,
    int M, int N, int K)
{
    __shared__ float As[16][65];
    __shared__ float Bs[16][65];
    const int tid = threadIdx.x;
    const int tx = tid & 15, ty = tid >> 4;
    const int brow = blockIdx.y * 64, bcol = blockIdx.x * 64;

    float acc[4][4] = {};
    for (int kt = 0; kt < K; kt += 16) {
        for (int i = tid; i < 64 * 16; i += 256) {
            int r = i >> 4, k = i & 15;
            As[k][r] = x[(long)(brow + r) * K + kt + k];
        }
        for (int i = tid; i < 64 * 16; i += 256) {
            int n = i >> 4, k = i & 15;
            Bs[k][n] = (w[(long)(bcol + n) * K + kt + k] > 0.5f) ? 1.f : 0.f;
        }
        __syncthreads();
#pragma unroll
        for (int k = 0; k < 16; ++k) {
            float a[4], b[4];
#pragma unroll
            for (int i = 0; i < 4; ++i) a[i] = As[k][ty * 4 + i];
#pragma unroll
            for (int j = 0; j < 4; ++j) b[j] = Bs[k][tx * 4 + j];
#pragma unroll
            for (int i = 0; i < 4; ++i)
#pragma unroll
                for (int j = 0; j < 4; ++j)
                    acc[i][j] += a[i] * b[j];
        }
        __syncthreads();
    }
#pragma unroll
    for (int i = 0; i < 4; ++i)
#pragma unroll
        for (int j = 0; j < 4; ++j)
            C[(long)(brow + ty * 4 + i) * N + bcol + tx * 4 + j] = acc[i][j] + bias[bcol + tx * 4 + j];
}

// ---------- launcher ----------

extern "C" void kernel_launch(void* const* d_in, const int* in_sizes, int n_in,
                              void* d_out, int out_size, void* d_ws, size_t ws_size,
                              hipStream_t stream) {
    const float* x    = (const float*)d_in[0];
    const float* w    = (const float*)d_in[1];
    const float* bias = (const float*)d_in[2];
    float* out = (float*)d_out;

    const int N = in_sizes[2];                 // 4096
    const int K = in_sizes[1] / N;             // 4096
    const int M = in_sizes[0] / K;             // 8192

    const size_t need = (size_t)M * K + (size_t)N * K + (size_t)M * 4;
    const int ngrid = (M / BM) * (N / BN);     // 32*32 = 1024
    const bool ok = (ws_size >= need) && (M % BM == 0) && (N % BN == 0)
                    && (K % (2 * BK) == 0) && (K / BK >= 4) && (ngrid % 8 == 0);

    if (ok) {
        signed char* xq = (signed char*)d_ws;
        signed char* wq = xq + (size_t)M * K;
        float* rscale   = (float*)(wq + (size_t)N * K);

        lb_quant_x<<<M, 256, 0, stream>>>(x, xq, rscale, K);
        long nw16 = (long)N * K / 16;
        lb_bin_w8<<<2048, 256, 0, stream>>>(w, (int4*)wq, nw16);

        lb_gemm_i8_direct<<<dim3(ngrid), 256, 0, stream>>>(xq, wq, rscale, bias, out, M, N, K);
    } else {
        dim3 grid(N / 64, M / 64);
        lb_gemm_fb<<<grid, 256, 0, stream>>>(x, w, bias, out, M, N, K);
    }
}